// Round 1
// baseline (324.346 us; speedup 1.0000x reference)
//
#include <hip/hip_runtime.h>

#define BSZ 8
#define SEQ 16
#define DIMN 512
#define SP 4096
#define KVL 4112

#define SCALE 0.0625f   // (512/2)^-0.5

// workspace layout (float offsets)
#define PPART 0                      // 3 * 4 * 128 * 512 = 786432
#define QBUF  786432                 // 65536
#define KNEW  851968                 // 65536
#define VNEW  917504                 // 65536
#define PROBS 983040                 // 8*16*4112 = 526336
#define APART 1509376                // 65 * 65536 = 4259840
#define ATTEN 5769216                // 65536
#define OPART 5834752                // 4 * 65536 = 262144

// ---------------------------------------------------------------------------
// Kernel A: partial projection  out[row][e] += sum_{d in dt-range} X[row][d]*W[e][d]
// grid (8b*4et, 4dt, nm), block 64.  Thread owns 8 rows x 4 e-cols over 128 d.
// ---------------------------------------------------------------------------
__global__ __launch_bounds__(64) void proj_partial(
    const float* __restrict__ X, const float* __restrict__ W0,
    const float* __restrict__ W1, const float* __restrict__ W2,
    float* __restrict__ outbase)
{
  __shared__ float xs[SEQ][128];
  int b = blockIdx.x >> 2, et = blockIdx.x & 3;
  int dt = blockIdx.y, m = blockIdx.z;
  const float* W = (m == 0) ? W0 : (m == 1) ? W1 : W2;
  float* outp = outbase + (size_t)m * (4 * 65536) + (size_t)dt * 65536;
  int t = threadIdx.x;

  const float4* xsrc = (const float4*)(X + (size_t)(b * SEQ) * DIMN + dt * 128);
  for (int i = t; i < SEQ * 32; i += 64) {
    int row = i >> 5, j = i & 31;
    *(float4*)&xs[row][j * 4] = xsrc[row * 128 + j];
  }
  __syncthreads();

  int r0 = (t >> 5) * 8;
  int e = et * 128 + (t & 31) * 4;
  float acc[8][4];
#pragma unroll
  for (int r = 0; r < 8; ++r)
#pragma unroll
    for (int i = 0; i < 4; ++i) acc[r][i] = 0.f;

  const float* wbase = W + dt * 128;
  for (int d4 = 0; d4 < 32; ++d4) {
    float4 w[4];
#pragma unroll
    for (int i = 0; i < 4; ++i)
      w[i] = *(const float4*)(wbase + (size_t)(e + i) * DIMN + d4 * 4);
#pragma unroll
    for (int r = 0; r < 8; ++r) {
      float4 xv = *(const float4*)&xs[r0 + r][d4 * 4];
#pragma unroll
      for (int i = 0; i < 4; ++i)
        acc[r][i] += xv.x * w[i].x + xv.y * w[i].y + xv.z * w[i].z + xv.w * w[i].w;
    }
  }
#pragma unroll
  for (int r = 0; r < 8; ++r) {
    float4 o = make_float4(acc[r][0], acc[r][1], acc[r][2], acc[r][3]);
    *(float4*)(outp + (size_t)(b * SEQ + r0 + r) * DIMN + e) = o;
  }
}

// ---------------------------------------------------------------------------
// Kernel B: reduce 4 d-partials.  src layout [m][dt][65536], dst [m*65536+j]
// ---------------------------------------------------------------------------
__global__ __launch_bounds__(256) void reduce_dt(
    const float* __restrict__ src, float* __restrict__ dst, int nm)
{
  int idx = blockIdx.x * 256 + threadIdx.x;
  if (idx >= nm * 65536) return;
  int m = idx >> 16, j = idx & 65535;
  const float* s = src + (size_t)m * (4 * 65536);
  dst[idx] = s[j] + s[65536 + j] + s[2 * 65536 + j] + s[3 * 65536 + j];
}

// ---------------------------------------------------------------------------
// Kernel C: scores.  One wave per position; lane holds q[.., lane*8..lane*8+7]
// for all 16 queries in regs; tree cross-lane reduction (ownership halving).
// grid (8, 65 chunks of 64 pos), block 256 (4 waves, interleaved positions).
// ---------------------------------------------------------------------------
__global__ __launch_bounds__(256) void scores_kernel(
    const float* __restrict__ qbuf, const float* __restrict__ cache_k,
    const float* __restrict__ knew, float* __restrict__ weight)
{
  int b = blockIdx.x;
  int p0 = blockIdx.y * 64;
  int len = KVL - p0; if (len > 64) len = 64;
  int t = threadIdx.x, lane = t & 63, w = t >> 6;

  float4 qa[SEQ], qb[SEQ];
  const float* qbase = qbuf + (size_t)b * SEQ * DIMN + lane * 8;
#pragma unroll
  for (int s = 0; s < SEQ; ++s) {
    qa[s] = *(const float4*)(qbase + s * DIMN);
    qb[s] = *(const float4*)(qbase + s * DIMN + 4);
  }

  bool b1 = (lane & 1), b2 = (lane & 2), b4 = (lane & 4), b8 = (lane & 8);
  int niter = (len - w + 3) >> 2;   // positions p0 + w + 4*i
#pragma unroll 2
  for (int i = 0; i < niter; ++i) {
    int p = p0 + w + 4 * i;
    const float* krow = (p < SP)
        ? (cache_k + ((size_t)b * 8192 + p) * DIMN)
        : (knew + (size_t)(b * SEQ + (p - SP)) * DIMN);
    float4 ka = *(const float4*)(krow + lane * 8);
    float4 kb = *(const float4*)(krow + lane * 8 + 4);

    float acc[SEQ];
#pragma unroll
    for (int s = 0; s < SEQ; ++s) {
      acc[s] = qa[s].x * ka.x + qa[s].y * ka.y + qa[s].z * ka.z + qa[s].w * ka.w
             + qb[s].x * kb.x + qb[s].y * kb.y + qb[s].z * kb.z + qb[s].w * kb.w;
    }
    // tree reduction: halve owned set each stage, exchange non-kept half
    float r8[8];
#pragma unroll
    for (int u = 0; u < 8; ++u) {
      float keep = b1 ? acc[u + 8] : acc[u];
      float send = b1 ? acc[u] : acc[u + 8];
      r8[u] = keep + __shfl_xor(send, 1);
    }
    float r4[4];
#pragma unroll
    for (int u = 0; u < 4; ++u) {
      float keep = b2 ? r8[u + 4] : r8[u];
      float send = b2 ? r8[u] : r8[u + 4];
      r4[u] = keep + __shfl_xor(send, 2);
    }
    float r2[2];
#pragma unroll
    for (int u = 0; u < 2; ++u) {
      float keep = b4 ? r4[u + 2] : r4[u];
      float send = b4 ? r4[u] : r4[u + 2];
      r2[u] = keep + __shfl_xor(send, 4);
    }
    float keep = b8 ? r2[1] : r2[0];
    float send = b8 ? r2[0] : r2[1];
    float r1 = keep + __shfl_xor(send, 8);
    r1 += __shfl_xor(r1, 16);
    r1 += __shfl_xor(r1, 32);

    if (lane < 16) {
      int s = ((lane & 1) << 3) | ((lane & 2) << 1) | ((lane & 4) >> 1) | ((lane & 8) >> 3);
      weight[(size_t)(b * SEQ + s) * KVL + p] = r1 * SCALE;
    }
  }
}

// ---------------------------------------------------------------------------
// Kernel D: softmax over KVL per (b,s) row.  probs = softmax(weight + mask)
// ---------------------------------------------------------------------------
__global__ __launch_bounds__(256) void softmax_kernel(
    const float* __restrict__ weight, const float* __restrict__ mask,
    float* __restrict__ probs)
{
  int row = blockIdx.x;          // b*16 + s
  int s = row & 15;
  int t = threadIdx.x, lane = t & 63, w = t >> 6;
  const float* src = weight + (size_t)row * KVL;
  const float* msk = mask + (size_t)s * KVL;

  float vals[17];
  float mx = -1e30f;
#pragma unroll
  for (int i = 0; i < 17; ++i) {
    int p = t + i * 256;
    if (p < KVL) { vals[i] = src[p] + msk[p]; mx = fmaxf(mx, vals[i]); }
    else vals[i] = -1e30f;
  }
  for (int off = 32; off >= 1; off >>= 1) mx = fmaxf(mx, __shfl_xor(mx, off));
  __shared__ float redm[4], reds[4];
  if (lane == 0) redm[w] = mx;
  __syncthreads();
  mx = fmaxf(fmaxf(redm[0], redm[1]), fmaxf(redm[2], redm[3]));

  float sum = 0.f;
#pragma unroll
  for (int i = 0; i < 17; ++i) {
    int p = t + i * 256;
    if (p < KVL) { vals[i] = __expf(vals[i] - mx); sum += vals[i]; }
  }
  for (int off = 32; off >= 1; off >>= 1) sum += __shfl_xor(sum, off);
  if (lane == 0) reds[w] = sum;
  __syncthreads();
  sum = reds[0] + reds[1] + reds[2] + reds[3];
  float inv = 1.0f / sum;

  float* dst = probs + (size_t)row * KVL;
#pragma unroll
  for (int i = 0; i < 17; ++i) {
    int p = t + i * 256;
    if (p < KVL) dst[p] = vals[i] * inv;
  }
}

// ---------------------------------------------------------------------------
// Kernel E: atten partials.  grid (8, 65 chunks of 64 pos), block 256.
// Thread owns v-cols {t, t+256} for all 16 queries; probs chunk staged in LDS.
// ---------------------------------------------------------------------------
__global__ __launch_bounds__(256) void attnv_kernel(
    const float* __restrict__ probs, const float* __restrict__ cache_v,
    const float* __restrict__ vnew, float* __restrict__ apart)
{
  __shared__ float pl[SEQ][64];
  int b = blockIdx.x, c = blockIdx.y;
  int p0 = c * 64;
  int len = KVL - p0; if (len > 64) len = 64;
  int t = threadIdx.x;

  for (int i = t; i < SEQ * 64; i += 256) {
    int q = i >> 6, j = i & 63;
    pl[q][j] = (j < len) ? probs[(size_t)(b * SEQ + q) * KVL + p0 + j] : 0.f;
  }
  __syncthreads();

  float acc0[SEQ], acc1[SEQ];
#pragma unroll
  for (int q = 0; q < SEQ; ++q) { acc0[q] = 0.f; acc1[q] = 0.f; }

  int nj4 = len >> 2;   // 16 or 4
  for (int j4 = 0; j4 < nj4; ++j4) {
    float4 pv[SEQ];
#pragma unroll
    for (int q = 0; q < SEQ; ++q) pv[q] = *(const float4*)&pl[q][j4 * 4];
#pragma unroll
    for (int jj = 0; jj < 4; ++jj) {
      int p = p0 + j4 * 4 + jj;
      const float* vrow = (p < SP)
          ? (cache_v + ((size_t)b * 8192 + p) * DIMN)
          : (vnew + (size_t)(b * SEQ + (p - SP)) * DIMN);
      float va = vrow[t], vb = vrow[t + 256];
#pragma unroll
      for (int q = 0; q < SEQ; ++q) {
        float pj = (jj == 0) ? pv[q].x : (jj == 1) ? pv[q].y : (jj == 2) ? pv[q].z : pv[q].w;
        acc0[q] += pj * va;
        acc1[q] += pj * vb;
      }
    }
  }
  float* outp = apart + (size_t)c * 65536 + (size_t)b * SEQ * DIMN;
#pragma unroll
  for (int q = 0; q < SEQ; ++q) {
    outp[q * DIMN + t] = acc0[q];
    outp[q * DIMN + t + 256] = acc1[q];
  }
}

// ---------------------------------------------------------------------------
// Kernel F: reduce 65 position-chunk partials -> atten
// ---------------------------------------------------------------------------
__global__ __launch_bounds__(256) void reduce_att(
    const float* __restrict__ apart, float* __restrict__ atten)
{
  int idx = blockIdx.x * 256 + threadIdx.x;   // grid 256 -> 65536
  float s = 0.f;
  for (int c = 0; c < 65; ++c) s += apart[(size_t)c * 65536 + idx];
  atten[idx] = s;
}

// ---------------------------------------------------------------------------
extern "C" void kernel_launch(void* const* d_in, const int* in_sizes, int n_in,
                              void* d_out, int out_size, void* d_ws, size_t ws_size,
                              hipStream_t stream) {
  const float* x       = (const float*)d_in[0];
  // d_in[1] = start_pos (fixed 4096, baked into constants)
  const float* mask    = (const float*)d_in[2];
  const float* Wq      = (const float*)d_in[3];
  const float* Wk      = (const float*)d_in[4];
  const float* Wv      = (const float*)d_in[5];
  const float* Wo      = (const float*)d_in[6];
  const float* cache_k = (const float*)d_in[7];
  const float* cache_v = (const float*)d_in[8];
  float* out    = (float*)d_out;           // [8,16,512]
  float* weight = out + 65536;             // [8,16,4112]
  float* ws     = (float*)d_ws;

  // q/k/v projections (split-K partials, then reduce)
  proj_partial<<<dim3(32, 4, 3), 64, 0, stream>>>(x, Wq, Wk, Wv, ws + PPART);
  reduce_dt<<<dim3(768), 256, 0, stream>>>(ws + PPART, ws + QBUF, 3);
  // scores -> weight output (pre-mask, scaled)
  scores_kernel<<<dim3(8, 65), 256, 0, stream>>>(ws + QBUF, cache_k, ws + KNEW, weight);
  // softmax(weight + mask) -> probs
  softmax_kernel<<<dim3(128), 256, 0, stream>>>(weight, mask, ws + PROBS);
  // probs @ v_full (split over position chunks)
  attnv_kernel<<<dim3(8, 65), 256, 0, stream>>>(ws + PROBS, cache_v, ws + VNEW, ws + APART);
  reduce_att<<<dim3(256), 256, 0, stream>>>(ws + APART, ws + ATTEN);
  // output projection
  proj_partial<<<dim3(32, 4, 1), 64, 0, stream>>>(ws + ATTEN, Wo, Wo, Wo, ws + OPART);
  reduce_dt<<<dim3(256), 256, 0, stream>>>(ws + OPART, out, 1);
}